// Round 7
// baseline (111.263 us; speedup 1.0000x reference)
//
#include <hip/hip_runtime.h>

#define NN 1024
#define BB 8
#define HH 8
#define FF 64
#define HF 512
#define KT 128

// ---------------- K1: fully self-contained prep
//  bx 0..1023   : wh GEMM full-K (2 nodes x 256-col half) + es/ed/edT epilogue
//  bx 1024..1039: whv2 K-half partials (b, kh) + bv partials
//  bx 1040..1295: adjacency compaction (4 rows/block)
//  bx 1296      : zero out
__global__ void __launch_bounds__(256) k_prep(
    const float* __restrict__ lab, const float* __restrict__ vis,
    const float* __restrict__ adj, const float* __restrict__ Wm,
    const float* __restrict__ a_src, const float* __restrict__ a_dst,
    float* __restrict__ wh, float* __restrict__ whv2, float* __restrict__ bvp,
    float* __restrict__ es, float* __restrict__ ed, float* __restrict__ edT,
    int* __restrict__ list, int* __restrict__ cnt, float* __restrict__ outp)
{
    int bx = blockIdx.x, t = threadIdx.x;
    __shared__ float sh[512];
    __shared__ float whs[2][256];
    if (bx < 1024) {
        int np = bx >> 1, ch = bx & 1, n0 = np * 2;
        sh[t]       = lab[n0 * 256 + t];
        sh[256 + t] = lab[(n0 + 1) * 256 + t];
        __syncthreads();
        float a0 = 0.f, a1 = 0.f;
        const float* wp = Wm + ch * 256 + t;
        #pragma unroll 8
        for (int i = 0; i < 256; ++i) {
            float w = wp[(size_t)i * HF];
            a0 += sh[i] * w;
            a1 += sh[256 + i] * w;
        }
        wh[(size_t)n0 * HF + ch * 256 + t]       = a0;
        wh[(size_t)(n0 + 1) * HF + ch * 256 + t] = a1;
        whs[0][t] = a0; whs[1][t] = a1;
        __syncthreads();
        if (t < 16) {
            int nd = t >> 3, rest = t & 7, hl = rest >> 1, sd = rest & 1;
            int h = ch * 4 + hl;
            const float* av = (sd ? a_dst : a_src) + h * FF;
            const float* wr = whs[nd] + hl * FF;
            float s = 0.f;
            #pragma unroll
            for (int f = 0; f < FF; ++f) s += wr[f] * av[f];
            int n = n0 + nd;
            if (sd) { ed[n * HH + h] = s; edT[h * NN + n] = s; }
            else es[n * HH + h] = s;
        }
    } else if (bx < 1040) {
        int id = bx - 1024, b = id >> 1, kh = id & 1;
        if (t < 256) sh[t] = vis[b * 512 + kh * 256 + t];
        __syncthreads();
        float a0 = 0.f, a1 = 0.f;
        const float* wp = Wm + (size_t)(256 + kh * 256) * HF;
        #pragma unroll 4
        for (int i = 0; i < 256; ++i) {
            float xv = sh[i];
            a0 += xv * wp[(size_t)i * HF + t];
            a1 += xv * wp[(size_t)i * HF + t + 256];
        }
        float* dst = whv2 + (size_t)(kh * BB + b) * HF;
        dst[t] = a0; dst[t + 256] = a1;
        __shared__ float wb[512];
        wb[t] = a0; wb[t + 256] = a1;
        __syncthreads();
        if (t < 8) {
            const float* as = a_src + t * FF;
            const float* ad = a_dst + t * FF;
            const float* wr = wb + t * FF;
            float s = 0.f;
            #pragma unroll 8
            for (int f = 0; f < FF; ++f) s += wr[f] * (as[f] + ad[f]);
            bvp[kh * 64 + b * 8 + t] = s;
        }
    } else if (bx < 1296) {
        int id = bx - 1040;
        int i = id * 4 + (t >> 6), lane = t & 63;
        int base = 0;
        for (int c = 0; c < 16; ++c) {
            int j = c * 64 + lane;
            bool pres = adj[(size_t)i * NN + j] > 0.f;
            unsigned long long m = __ballot(pres);
            int pos = __popcll(m & ((1ull << lane) - 1ull));
            if (pres) list[i * NN + base + pos] = j;
            base += __popcll(m);
        }
        if (lane == 0) cnt[i] = base;
    } else {
        float4 z; z.x = 0.f; z.y = 0.f; z.z = 0.f; z.w = 0.f;
        float4* oo = (float4*)outp;
        #pragma unroll
        for (int q = 0; q < 4; ++q) oo[q * 256 + t] = z;
    }
}

// ---------------- K2: attention (feature-half split z; self-computed edmax/bv)
__global__ void __launch_bounds__(256) k_attn(
    const float* __restrict__ wh, const float* __restrict__ whv2,
    const float* __restrict__ es, const float* __restrict__ ed,
    const float* __restrict__ edT, const float* __restrict__ bvp,
    const int* __restrict__ list, const int* __restrict__ cnt,
    const float* __restrict__ pool_q,
    float* __restrict__ xout, float* __restrict__ scores_half)
{
    int i = blockIdx.x, z = blockIdx.y, t = threadIdx.x;
    int nn = cnt[i];

    __shared__ float att[(KT + 2) * 32];   // [k][hl*8+b]; reused as merge buffer
    __shared__ int jl[KT + 2];
    __shared__ float base_s[32], M_s[32], inv_s[32];
    __shared__ float red[8][32];
    __shared__ float red2[4][BB];
    __shared__ float edmax_z[4];

    // prologue A: per-head global ed max (one wave per head-local)
    {
        int hl = t >> 6, h = z * 4 + hl;
        const float* col = edT + h * NN;
        float m = -1e30f;
        #pragma unroll
        for (int g = 0; g < 16; ++g) m = fmaxf(m, col[(t & 63) + g * 64]);
        #pragma unroll
        for (int off = 32; off > 0; off >>= 1) m = fmaxf(m, __shfl_down(m, off));
        if ((t & 63) == 0) edmax_z[hl] = m;
    }
    __syncthreads();
    if (t < 32) {
        int hl = t >> 3, b = t & 7, h = z * 4 + hl;
        float base = es[i * HH + h] + bvp[b * 8 + h] + bvp[64 + b * 8 + h];
        base_s[t] = base;
        float mv = base + edmax_z[hl];       // >= any neighbor's pre-leaky e
        M_s[t] = mv > 0.f ? mv : 0.2f * mv;  // leaky monotone -> valid upper bound
    }
    __syncthreads();

    int p = t & 31;
    int hp = z * 4 + (p >> 3);
    float basev = base_s[p], Mv = M_s[p];
    float ssum = 0.f;

    int kp = t >> 7;          // 0/1: which parity of k this thread aggregates
    int tf = t & 127;         // feature-pair lane
    int f0 = z * 256 + 2 * tf;
    int hl8 = (tf >> 5) * 8;
    float ac[16];
    #pragma unroll
    for (int q = 0; q < 16; ++q) ac[q] = 0.f;

    for (int c0 = 0; c0 < nn; c0 += KT) {
        int kc = min(KT, nn - c0);
        int kc2 = (kc + 1) & ~1;
        __syncthreads();
        if (t < kc) jl[t] = list[i * NN + c0 + t];
        else if (t < kc2) jl[t] = 0;
        __syncthreads();
        for (int k = t >> 5; k < kc; k += 8) {
            int j = jl[k];
            float e = basev + ed[j * HH + hp];
            e = e > 0.f ? e : 0.2f * e;
            float pe = __expf(e - Mv);
            ssum += pe;
            att[k * 32 + p] = pe;
        }
        if ((kc & 1) && t < 32) att[kc * 32 + t] = 0.f;
        __syncthreads();
        #pragma unroll 2
        for (int k = 0; k < kc2; k += 2) {
            int kk = k + kp;
            const float2 r = *(const float2*)&wh[(size_t)jl[kk] * HF + f0];
            const float4 aA = *(const float4*)&att[kk * 32 + hl8];
            const float4 aB = *(const float4*)&att[kk * 32 + hl8 + 4];
            ac[0]  += aA.x * r.x; ac[1]  += aA.x * r.y;
            ac[2]  += aA.y * r.x; ac[3]  += aA.y * r.y;
            ac[4]  += aA.z * r.x; ac[5]  += aA.z * r.y;
            ac[6]  += aA.w * r.x; ac[7]  += aA.w * r.y;
            ac[8]  += aB.x * r.x; ac[9]  += aB.x * r.y;
            ac[10] += aB.y * r.x; ac[11] += aB.y * r.y;
            ac[12] += aB.z * r.x; ac[13] += aB.z * r.y;
            ac[14] += aB.w * r.x; ac[15] += aB.w * r.y;
        }
    }
    __syncthreads();                       // all att reads done
    red[t >> 5][p] = ssum;
    float* mrg = (float*)att;              // reuse att space for kp-merge
    if (kp == 1) {
        #pragma unroll
        for (int q = 0; q < 16; ++q) mrg[tf * 16 + q] = ac[q];
    }
    __syncthreads();
    if (t < 32) {
        float s = 0.f;
        #pragma unroll
        for (int g = 0; g < 8; ++g) s += red[g][t];
        inv_s[t] = 1.0f / s;
    }
    __syncthreads();
    if (kp == 0) {
        #pragma unroll
        for (int q = 0; q < 16; ++q) ac[q] += mrg[tf * 16 + q];
    }

    int hl = tf >> 5;
    const float2 pq2 = *(const float2*)&pool_q[f0];
    #pragma unroll
    for (int b = 0; b < BB; ++b) {
        float spv = 0.f;
        if (kp == 0) {
            float iv = inv_s[hl * 8 + b];
            const float2 wva = *(const float2*)&whv2[(size_t)b * HF + f0];
            const float2 wvb = *(const float2*)&whv2[(size_t)(BB + b) * HF + f0];
            float o0 = ac[2 * b]     * iv + wva.x + wvb.x;
            float o1 = ac[2 * b + 1] * iv + wva.y + wvb.y;
            o0 = o0 > 0.f ? o0 : (__expf(o0) - 1.f);
            o1 = o1 > 0.f ? o1 : (__expf(o1) - 1.f);
            float2 ov; ov.x = o0; ov.y = o1;
            *(float2*)&xout[((size_t)b * NN + i) * HF + f0] = ov;
            spv = o0 * pq2.x + o1 * pq2.y;
        }
        #pragma unroll
        for (int off = 32; off > 0; off >>= 1) spv += __shfl_down(spv, off);
        if ((t & 63) == 0) red2[t >> 6][b] = spv;
    }
    __syncthreads();
    if (t < BB)
        scores_half[(z * BB + t) * NN + i] = red2[0][t] + red2[1][t] + red2[2][t] + red2[3][t];
}

// ---------------- K3: node softmax (redundant) + pool partial + fused FC partial
__global__ void __launch_bounds__(256) k_smax_pool_fc(const float* __restrict__ sch,
    const float* __restrict__ xout, const float* __restrict__ fc_W,
    const float* __restrict__ fc_b, float* __restrict__ out)
{
    int q = blockIdx.x, b = blockIdx.y, t = threadIdx.x;
    int lane = t & 63, wid = t >> 6;
    __shared__ float red[4];
    __shared__ float sM, sI;
    __shared__ float wl[64];
    __shared__ float pl[512];

    float v[4];
    float mx = -1e30f;
    #pragma unroll
    for (int qq = 0; qq < 4; ++qq) {
        int n = qq * 256 + t;
        v[qq] = sch[b * NN + n] + sch[(BB + b) * NN + n];
        mx = fmaxf(mx, v[qq]);
    }
    #pragma unroll
    for (int off = 32; off > 0; off >>= 1) mx = fmaxf(mx, __shfl_down(mx, off));
    if (lane == 0) red[wid] = mx;
    __syncthreads();
    if (t == 0) sM = fmaxf(fmaxf(red[0], red[1]), fmaxf(red[2], red[3]));
    __syncthreads();
    float sm = 0.f;
    #pragma unroll
    for (int qq = 0; qq < 4; ++qq) sm += __expf(v[qq] - sM);
    #pragma unroll
    for (int off = 32; off > 0; off >>= 1) sm += __shfl_down(sm, off);
    __syncthreads();
    if (lane == 0) red[wid] = sm;
    __syncthreads();
    if (t == 0) sI = 1.0f / (red[0] + red[1] + red[2] + red[3]);
    __syncthreads();

    if (t < 64) {
        int n = q * 64 + t;
        float s = sch[b * NN + n] + sch[(BB + b) * NN + n];
        wl[t] = __expf(s - sM) * sI;
    }
    __syncthreads();

    int f0 = 2 * t;
    float ax = 0.f, ay = 0.f;
    #pragma unroll 4
    for (int n = 0; n < 64; ++n) {
        float w = wl[n];
        const float2 r = *(const float2*)&xout[((size_t)b * NN + q * 64 + n) * HF + f0];
        ax += w * r.x; ay += w * r.y;
    }
    pl[f0] = ax; pl[f0 + 1] = ay;
    __syncthreads();

    // FC on this block's pooled partial (linearity of pooled -> FC)
    float ax2 = 0.f, ay2 = 0.f;
    if (q == 0) { ax2 = fc_b[f0]; ay2 = fc_b[f0 + 1]; }
    #pragma unroll 4
    for (int k = 0; k < 512; ++k) {
        float pv = pl[k];
        const float2 w2 = *(const float2*)&fc_W[(size_t)k * HF + f0];
        ax2 += pv * w2.x; ay2 += pv * w2.y;
    }
    atomicAdd(&out[b * HF + f0], ax2);
    atomicAdd(&out[b * HF + f0 + 1], ay2);
}

extern "C" void kernel_launch(void* const* d_in, const int* in_sizes, int n_in,
                              void* d_out, int out_size, void* d_ws, size_t ws_size,
                              hipStream_t stream) {
    const float* vis   = (const float*)d_in[0];
    const float* lab   = (const float*)d_in[1];
    const float* adj   = (const float*)d_in[2];
    const float* Wm    = (const float*)d_in[3];
    const float* a_src = (const float*)d_in[4];
    const float* a_dst = (const float*)d_in[5];
    const float* pq    = (const float*)d_in[6];
    const float* fcW   = (const float*)d_in[7];
    const float* fcb   = (const float*)d_in[8];
    float* out = (float*)d_out;

    char* w = (char*)d_ws;
    float* wh    = (float*)w;  w += (size_t)NN * HF * 4;       // 2 MB
    float* whv2  = (float*)w;  w += (size_t)2 * BB * HF * 4;   // 32 KB
    float* bvp   = (float*)w;  w += 2 * 64 * 4;
    float* es    = (float*)w;  w += (size_t)NN * HH * 4;
    float* ed    = (float*)w;  w += (size_t)NN * HH * 4;
    float* edT   = (float*)w;  w += (size_t)HH * NN * 4;
    int*   nlist = (int*)w;    w += (size_t)NN * NN * 4;       // 4 MB
    int*   ncnt  = (int*)w;    w += (size_t)NN * 4;
    float* xout  = (float*)w;  w += (size_t)BB * NN * HF * 4;  // 16 MB
    float* sch   = (float*)w;  w += (size_t)2 * BB * NN * 4;   // 64 KB

    k_prep<<<1297, 256, 0, stream>>>(lab, vis, adj, Wm, a_src, a_dst,
                                     wh, whv2, bvp, es, ed, edT, nlist, ncnt, out);
    k_attn<<<dim3(NN, 2), 256, 0, stream>>>(wh, whv2, es, ed, edT, bvp,
                                            nlist, ncnt, pq, xout, sch);
    k_smax_pool_fc<<<dim3(16, BB), 256, 0, stream>>>(sch, xout, fcW, fcb, out);
}